// Round 4
// baseline (272.222 us; speedup 1.0000x reference)
//
#include <hip/hip_runtime.h>
#include <stdint.h>

#define DIM 1024
#define SEQ 2048
#define NB 4

typedef unsigned short u16;
typedef __bf16 bf16x8 __attribute__((ext_vector_type(8)));
typedef float floatx4 __attribute__((ext_vector_type(4)));

__device__ __forceinline__ u16 f32_to_bf16(float f) {
  union { float f; unsigned u; } v; v.f = f;
  unsigned r = v.u + 0x7FFFu + ((v.u >> 16) & 1u);
  return (u16)(r >> 16);
}

__device__ __forceinline__ void async16(const void* g, void* l) {
  __builtin_amdgcn_global_load_lds(
      (__attribute__((address_space(1))) unsigned int*)g,
      (__attribute__((address_space(3))) unsigned int*)l, 16, 0, 0);
}

// ---------------- prep: x fp32->bf16 (16B stores)  +  W transpose ----------------
__global__ __launch_bounds__(256) void k_prep(const float* __restrict__ x,
                                              const float* __restrict__ Wq,
                                              const float* __restrict__ Wk,
                                              const float* __restrict__ Wv,
                                              u16* __restrict__ xb,
                                              u16* __restrict__ wt) {
  __shared__ u16 tile[32][33];
  const int bid = blockIdx.x;
  const int tid = threadIdx.x;
  if (bid < 4096) {                       // cvt: 4096 blocks x 256 x 8 floats
    int i = bid * 256 + tid;
    float4 a = ((const float4*)x)[i * 2];
    float4 b = ((const float4*)x)[i * 2 + 1];
    ushort4 o0, o1;
    o0.x = f32_to_bf16(a.x); o0.y = f32_to_bf16(a.y);
    o0.z = f32_to_bf16(a.z); o0.w = f32_to_bf16(a.w);
    o1.x = f32_to_bf16(b.x); o1.y = f32_to_bf16(b.y);
    o1.z = f32_to_bf16(b.z); o1.w = f32_to_bf16(b.w);
    ((ushort4*)xb)[i * 2] = o0;
    ((ushort4*)xb)[i * 2 + 1] = o1;
  } else {                                // transpose: 3 x 1024 tile-blocks
    int t = bid - 4096;
    int z = t >> 10;
    int ti = t & 1023;
    int c0 = (ti & 31) * 32, r0 = (ti >> 5) * 32;
    const float* src = (z == 0) ? Wq : (z == 1) ? Wk : Wv;
    u16* d = wt + (size_t)z * DIM * DIM;
    int tx = tid & 31, ty = tid >> 5;     // 32 x 8
    #pragma unroll
    for (int dy = 0; dy < 32; dy += 8)
      tile[ty + dy][tx] = f32_to_bf16(src[(size_t)(r0 + ty + dy) * DIM + c0 + tx]);
    __syncthreads();
    #pragma unroll
    for (int dy = 0; dy < 32; dy += 8)
      d[(size_t)(c0 + ty + dy) * DIM + r0 + tx] = tile[tx][ty + dy];
  }
}

// ============ 8-phase 256x256 GEMM core, REGISTER-PIPELINED, DEEP-STAGE ============
// 8 waves (2Mx4N), BK=64, 2 K-tiles/iteration across 8 phases.
// LDS = 4 slots of one K-tile each: A0 | A1 | B0 | B1 (32 KB each, 128 KB).
// Stage schedule compacted for >=2.3-phase issue->wait distance (HBM ~900cy):
//   ph0: A1 x4 (2t+1)   ph2: B0' x4 (2t+2)   ph3: A0' x4 (2t+2)
//   ph6: B1'h0 x2 (2t+3) ph7: B1'h1 x2
// Ledger (FIFO): ph2-end outstanding 12 -> vmcnt(4) retires through A1 (slot1
// ready for ph3 preload); ph6-end outstanding 10 -> vmcnt(2) retires through
// A0' (slot0' ready for ph7 preload). Final iter: vmcnt(0) @ ph2, no ph6 wait.

#define STG(PG, STBASE, SLOT, H, I, KT)                                        \
  async16((PG) + (size_t)((H) * 128 + (I) * 64) * DIM + (KT) * 64,             \
          (STBASE) + (SLOT) * 16384 + (H) * 8192 + (I) * 4096)

#define LOADAF(AF, SLOT, KS, MH)                                               \
  { const u16* pa_ = aRd + (SLOT) * 16384;                                     \
    const int g_ = (KS) ? ga1 : ga0;                                           \
    AF[0] = *(const bf16x8*)(pa_ + ((MH) * 4 + 0) * 1024 + g_);                \
    AF[1] = *(const bf16x8*)(pa_ + ((MH) * 4 + 1) * 1024 + g_);                \
    AF[2] = *(const bf16x8*)(pa_ + ((MH) * 4 + 2) * 1024 + g_);                \
    AF[3] = *(const bf16x8*)(pa_ + ((MH) * 4 + 3) * 1024 + g_); }

#define LOADBF(BF, SLOT, KS)                                                   \
  { const u16* pb_ = bRd + (SLOT) * 16384;                                     \
    const int g_ = (KS) ? ga1 : ga0;                                           \
    BF[0] = *(const bf16x8*)(pb_ + 0 * 1024 + g_);                             \
    BF[1] = *(const bf16x8*)(pb_ + 1 * 1024 + g_);                             \
    BF[2] = *(const bf16x8*)(pb_ + 2 * 1024 + g_);                             \
    BF[3] = *(const bf16x8*)(pb_ + 3 * 1024 + g_); }

#define MFMA16(AFU, BFU, MH)                                                   \
  _Pragma("unroll") for (int m_ = 0; m_ < 4; ++m_)                             \
      _Pragma("unroll") for (int n_ = 0; n_ < 4; ++n_)                         \
          acc[(MH) * 4 + m_][n_] = __builtin_amdgcn_mfma_f32_16x16x32_bf16(    \
              AFU[m_], BFU[n_], acc[(MH) * 4 + m_][n_], 0, 0, 0);

#define PH(AFU, BFU, MH, PRELOAD, STGS, SYNC)                                  \
  {                                                                            \
    PRELOAD                                                                    \
    STGS                                                                       \
    __builtin_amdgcn_s_barrier();                                              \
    __builtin_amdgcn_s_setprio(1);                                             \
    MFMA16(AFU, BFU, MH);                                                      \
    __builtin_amdgcn_s_setprio(0);                                             \
    asm volatile("s_waitcnt lgkmcnt(0)" ::: "memory");                         \
    __builtin_amdgcn_sched_barrier(0);                                         \
    SYNC                                                                       \
    __builtin_amdgcn_s_barrier();                                              \
  }

// jobs: [0,128) q tiles, [128,256) k tiles, [256,384) vT tiles. 384%8==0 so the
// simple XCD swizzle is bijective; each XCD gets 48 consecutive tile ids.
__global__ __launch_bounds__(512) void k_proj8(const u16* __restrict__ xb,
                                               const u16* __restrict__ wt,
                                               u16* __restrict__ qk,
                                               u16* __restrict__ vT) {
  __shared__ u16 lds[65536];               // 128 KB: A0|A1|B0|B1
  const int wg = ((blockIdx.x & 7) * 48) + (blockIdx.x >> 3);
  const int tid = threadIdx.x;
  const int lane = tid & 63;
  const int wid = tid >> 6;

  const u16 *A, *Bt;
  u16* Cout;
  int ldc;
  if (wg < 256) {
    const int z = wg >> 7;                 // 0=q, 1=k
    const int r = wg & 127;
    const int mt = r >> 2, nt = r & 3;     // 32 x 4 tiles of 256x256
    A = xb + (size_t)mt * 256 * DIM;
    Bt = wt + (size_t)z * DIM * DIM + (size_t)nt * 256 * DIM;
    Cout = qk + (size_t)z * (NB * SEQ * DIM) + (size_t)mt * 256 * DIM + nt * 256;
    ldc = DIM;
  } else {                                 // vT = Wv^T @ x^T
    const int r = wg - 256;
    const int mt = r & 3, nt = r >> 2;     // mt inner: 4 blocks sharing an xb
                                           // panel land on the SAME XCD (L2 fix)
    A = wt + (size_t)2 * DIM * DIM + (size_t)mt * 256 * DIM;
    Bt = xb + (size_t)nt * 256 * DIM;
    Cout = vT + (size_t)(nt >> 3) * (DIM * SEQ) + (size_t)mt * 256 * SEQ
              + (nt & 7) * 256;
    ldc = SEQ;
  }

  // staging: per issue, wave covers 8 rows x 8 granules; pre-swizzled source.
  const int srow = wid * 8 + (lane >> 3);
  const int gsrc = (lane & 7) ^ ((lane >> 3) & 7);
  const u16* pga = A + (size_t)srow * DIM + gsrc * 8;
  const u16* pgb = Bt + (size_t)srow * DIM + gsrc * 8;
  u16* stA = lds + wid * 512;              // wave-uniform LDS dest bases
  u16* stB = lds + 32768 + wid * 512;

  // compute-side addressing
  const int wr = wid >> 2, wc = wid & 3;
  const int lrow = lane & 15, quad = lane >> 4;
  const int s = lrow & 7;
  const u16* aRd = lds + (wr * 128 + lrow) * 64;
  const u16* bRd = lds + 32768 + (wc * 64 + lrow) * 64;
  const int ga0 = (quad ^ s) << 3;         // ksub0 granule (u16 offset)
  const int ga1 = ga0 ^ 32;                // ksub1

  floatx4 acc[8][4] = {};
  bf16x8 afA[4], afB[4], bfrP[4], bfrQ[4];

  // prologue: K0 -> A0,B0 (8 issues), K1 -> B1 h0+h1 (4 issues)
  STG(pga, stA, 0, 0, 0, 0); STG(pga, stA, 0, 0, 1, 0);
  STG(pga, stA, 0, 1, 0, 0); STG(pga, stA, 0, 1, 1, 0);
  STG(pgb, stB, 0, 0, 0, 0); STG(pgb, stB, 0, 0, 1, 0);
  STG(pgb, stB, 0, 1, 0, 0); STG(pgb, stB, 0, 1, 1, 0);
  STG(pgb, stB, 1, 0, 0, 1); STG(pgb, stB, 1, 0, 1, 1);
  STG(pgb, stB, 1, 1, 0, 1); STG(pgb, stB, 1, 1, 1, 1);
  asm volatile("s_waitcnt vmcnt(4)" ::: "memory");   // slot0 (first 8) landed
  __builtin_amdgcn_s_barrier();
  // preload phase-0 fragments
  LOADAF(afA, 0, 0, 0);
  LOADBF(bfrP, 0, 0);
  asm volatile("s_waitcnt lgkmcnt(0)" ::: "memory");
  __builtin_amdgcn_sched_barrier(0);

  const int NITER = DIM / 128;             // 8 iterations, 2 K-tiles each
  for (int t = 0; t < NITER; ++t) {
    const bool more = (t + 1 < NITER);
    const int kA1 = 2 * t + 1;             // slot1-A content for this iter
    const int kN = 2 * t + 2;              // next slot0 content
    const int kB1n = 2 * t + 3;            // next slot1-B content

    // ph0: MFMA s0/k0/m0 (afA,bfrP); preload af(ph1); stage A1 FULL (x4)
    PH(afA, bfrP, 0,
       LOADAF(afB, 0, 0, 1);,
       STG(pga, stA, 1, 0, 0, kA1); STG(pga, stA, 1, 0, 1, kA1);
       STG(pga, stA, 1, 1, 0, kA1); STG(pga, stA, 1, 1, 1, kA1);, {})
    // ph1: MFMA s0/k0/m1 (afB,bfrP); preload af+bfr(ph2); no stage
    PH(afB, bfrP, 1,
       LOADAF(afA, 0, 1, 0); LOADBF(bfrQ, 0, 1);,
       {}, {})
    // ph2: MFMA s0/k1/m0 (afA,bfrQ); preload af(ph3); stage B0' FULL; SYNC slot1
    PH(afA, bfrQ, 0,
       LOADAF(afB, 0, 1, 1);,
       if (more) { STG(pgb, stB, 0, 0, 0, kN); STG(pgb, stB, 0, 0, 1, kN);
                   STG(pgb, stB, 0, 1, 0, kN); STG(pgb, stB, 0, 1, 1, kN); },
       if (more) { asm volatile("s_waitcnt vmcnt(4)" ::: "memory"); }
       else      { asm volatile("s_waitcnt vmcnt(0)" ::: "memory"); })
    // ph3: MFMA s0/k1/m1 (afB,bfrQ); preload af+bfr(ph4, slot1); stage A0' FULL
    PH(afB, bfrQ, 1,
       LOADAF(afA, 1, 0, 0); LOADBF(bfrP, 1, 0);,
       if (more) { STG(pga, stA, 0, 0, 0, kN); STG(pga, stA, 0, 0, 1, kN);
                   STG(pga, stA, 0, 1, 0, kN); STG(pga, stA, 0, 1, 1, kN); }, {})
    // ph4: MFMA s1/k0/m0 (afA,bfrP); preload af(ph5); no stage
    PH(afA, bfrP, 0,
       LOADAF(afB, 1, 0, 1);,
       {}, {})
    // ph5: MFMA s1/k0/m1 (afB,bfrP); preload af+bfr(ph6); no stage
    PH(afB, bfrP, 1,
       LOADAF(afA, 1, 1, 0); LOADBF(bfrQ, 1, 1);,
       {}, {})
    // ph6: MFMA s1/k1/m0 (afA,bfrQ); preload af(ph7); stage B1' h0; SYNC slot0'
    PH(afA, bfrQ, 0,
       LOADAF(afB, 1, 1, 1);,
       if (more) { STG(pgb, stB, 1, 0, 0, kB1n); STG(pgb, stB, 1, 0, 1, kB1n); },
       if (more) { asm volatile("s_waitcnt vmcnt(2)" ::: "memory"); })
    // ph7: MFMA s1/k1/m1 (afB,bfrQ); preload af+bfr(next ph0, slot0'); stage B1' h1
    PH(afB, bfrQ, 1,
       if (more) { LOADAF(afA, 0, 0, 0); LOADBF(bfrP, 0, 0); },
       if (more) { STG(pgb, stB, 1, 1, 0, kB1n); STG(pgb, stB, 1, 1, 1, kB1n); }, {})
  }

  // insurance: ledger says vmcnt==0 here; this is free if so.
  asm volatile("s_waitcnt vmcnt(0)" ::: "memory");

  // epilogue: row = wr*128 + m*16 + quad*4 + rr, col = wc*64 + n*16 + lrow
  u16* C = Cout + (size_t)(wr * 128 + quad * 4) * ldc + wc * 64 + lrow;
  #pragma unroll
  for (int m = 0; m < 8; ++m)
    #pragma unroll
    for (int rr = 0; rr < 4; ++rr)
      #pragma unroll
      for (int n = 0; n < 4; ++n)
        C[(size_t)(m * 16 + rr) * ldc + n * 16] = f32_to_bf16(acc[m][n][rr]);
}

// ---------------- BK=128 MFMA core (scores/pv: grid-capped residency) ----------------
__device__ __forceinline__ void mfma_core128(const u16* __restrict__ A, int lda,
                                             const u16* __restrict__ Bt, int ldb,
                                             int kchunks, u16* lds,
                                             floatx4 acc[4][4]) {
  const int tid = threadIdx.x;
  const int lane = tid & 63;
  const int wid = tid >> 6;
  u16* lds_a = lds;            // 128 x 128 (swizzled granules)
  u16* lds_b = lds + 16384;

  const int srow4 = lane >> 4;          // 0..3
  const int sgr = lane & 15;
  const int gbase = sgr ^ srow4;        // even c
  const u16* ag0 = A + (size_t)(wid * 32 + srow4) * lda + gbase * 8;
  const u16* ag1 = A + (size_t)(wid * 32 + srow4) * lda + (gbase ^ 4) * 8;
  const u16* bg0 = Bt + (size_t)(wid * 32 + srow4) * ldb + gbase * 8;
  const u16* bg1 = Bt + (size_t)(wid * 32 + srow4) * ldb + (gbase ^ 4) * 8;
  u16* la = lds_a + wid * 4096;         // 32 rows x 128
  u16* lb = lds_b + wid * 4096;

  const int wm = (wid >> 1) * 64, wn = (wid & 1) * 64;
  const int lrow = lane & 15, quad = lane >> 4;
  const int s = lrow & 7;
  const u16* pa = lds_a + (wm + lrow) * 128;
  const u16* pb = lds_b + (wn + lrow) * 128;

  for (int kt = 0; kt < kchunks; ++kt) {
    #pragma unroll
    for (int c = 0; c < 8; ++c) {
      const u16* sa = ((c & 1) ? ag1 : ag0) + (size_t)(c * 4) * lda;
      async16(sa, la + c * 512);
    }
    #pragma unroll
    for (int c = 0; c < 8; ++c) {
      const u16* sb = ((c & 1) ? bg1 : bg0) + (size_t)(c * 4) * ldb;
      async16(sb, lb + c * 512);
    }
    ag0 += 128; ag1 += 128; bg0 += 128; bg1 += 128;
    __syncthreads();
    #pragma unroll
    for (int ks = 0; ks < 4; ++ks) {
      const int g = (((ks << 2) | quad) ^ s) << 3;
      bf16x8 af[4], bfr[4];
      #pragma unroll
      for (int t = 0; t < 4; ++t) af[t] = *(const bf16x8*)(pa + t * 2048 + g);
      #pragma unroll
      for (int t = 0; t < 4; ++t) bfr[t] = *(const bf16x8*)(pb + t * 2048 + g);
      #pragma unroll
      for (int i = 0; i < 4; ++i)
        #pragma unroll
        for (int j = 0; j < 4; ++j)
          acc[i][j] = __builtin_amdgcn_mfma_f32_16x16x32_bf16(af[i], bfr[j],
                                                              acc[i][j], 0, 0, 0);
    }
    __syncthreads();
  }
}

// ---------------- scores = (q @ k^T) * scale, exact lower-triangle grid ----------------
__global__ __launch_bounds__(256) void k_scores(const u16* __restrict__ q,
                                                const u16* __restrict__ k,
                                                float* __restrict__ w) {
  const int id = blockIdx.x;               // [0,544)
  const int b = id & 3;
  int t = id >> 2;                         // [0,136)
  int mt = (int)((sqrtf(8.0f * (float)t + 1.0f) - 1.0f) * 0.5f);
  while ((mt + 1) * (mt + 2) / 2 <= t) ++mt;
  while (mt * (mt + 1) / 2 > t) --mt;
  const int nt = t - mt * (mt + 1) / 2;
  __shared__ u16 lds[32768];
  floatx4 acc[4][4] = {};
  mfma_core128(q + (size_t)b * SEQ * DIM + (size_t)mt * 128 * DIM, DIM,
               k + (size_t)b * SEQ * DIM + (size_t)nt * 128 * DIM, DIM,
               DIM / 128, lds, acc);
  const int lane = threadIdx.x & 63, wid = threadIdx.x >> 6;
  const int wm = (wid >> 1) * 64, wn = (wid & 1) * 64;
  const int lrow = lane & 15, quad = lane >> 4;
  float* C = w + (size_t)b * SEQ * SEQ
               + (size_t)(mt * 128 + wm + quad * 4) * SEQ + nt * 128 + wn + lrow;
  #pragma unroll
  for (int i = 0; i < 4; ++i)
    #pragma unroll
    for (int rr = 0; rr < 4; ++rr)
      #pragma unroll
      for (int j = 0; j < 4; ++j)
        C[(size_t)(i * 16 + rr) * SEQ + j * 16] = acc[i][j][rr] * 0.03125f;
}

// ---------------- row softmax: weights fp32 (in-place) + P bf16 ----------------
__global__ __launch_bounds__(256) void k_softmax(float* __restrict__ w,
                                                 u16* __restrict__ P) {
  const int r = blockIdx.x;
  const int i = r & (SEQ - 1);
  const int len = i + 1;
  const int plen4 = (((i >> 7) + 1) << 7) >> 2;   // P write bound / float4
  float4* srow = (float4*)(w + (size_t)r * SEQ);
  ushort4* prow = (ushort4*)(P + (size_t)r * SEQ);
  const int tid = threadIdx.x;
  const int lane = tid & 63, wid = tid >> 6;
  __shared__ float rm[4], rs[4];

  float4 e[2];
  float mx = -1e30f;
  #pragma unroll
  for (int u = 0; u < 2; ++u) {
    int q4 = tid + u * 256;
    int j0 = q4 * 4;
    float4 v = make_float4(-1e30f, -1e30f, -1e30f, -1e30f);
    if (j0 < len) {
      v = srow[q4];
      v.x = (j0 + 0 < len) ? v.x : -1e30f;
      v.y = (j0 + 1 < len) ? v.y : -1e30f;
      v.z = (j0 + 2 < len) ? v.z : -1e30f;
      v.w = (j0 + 3 < len) ? v.w : -1e30f;
    }
    e[u] = v;
    mx = fmaxf(mx, fmaxf(fmaxf(v.x, v.y), fmaxf(v.z, v.w)));
  }
  #pragma unroll
  for (int o = 32; o >= 1; o >>= 1) mx = fmaxf(mx, __shfl_xor(mx, o, 64));
  if (lane == 0) rm[wid] = mx;
  __syncthreads();
  mx = fmaxf(fmaxf(rm[0], rm[1]), fmaxf(rm[2], rm[3]));

  float sum = 0.f;
  #pragma unroll
  for (int u = 0; u < 2; ++u) {
    e[u].x = __expf(e[u].x - mx);
    e[u].y = __expf(e[u].y - mx);
    e[u].z = __expf(e[u].z - mx);
    e[u].w = __expf(e[u].w - mx);
    sum += e[u].x + e[u].y + e[u].z + e[u].w;
  }
  #pragma unroll
  for (int o = 32; o >= 1; o >>= 1) sum += __shfl_xor(sum, o, 64);
  if (lane == 0) rs[wid] = sum;
  __syncthreads();
  sum = rs[0] + rs[1] + rs[2] + rs[3];
  const float inv = 1.0f / sum;

  #pragma unroll
  for (int u = 0; u < 2; ++u) {
    int q4 = tid + u * 256;
    int j0 = q4 * 4;
    float4 v;
    v.x = (j0 + 0 < len) ? e[u].x * inv : 0.f;
    v.y = (j0 + 1 < len) ? e[u].y * inv : 0.f;
    v.z = (j0 + 2 < len) ? e[u].z * inv : 0.f;
    v.w = (j0 + 3 < len) ? e[u].w * inv : 0.f;
    srow[q4] = v;                   // full fp32 row incl. zeros (output!)
    if (q4 < plen4) {
      ushort4 p;
      p.x = f32_to_bf16(v.x); p.y = f32_to_bf16(v.y);
      p.z = f32_to_bf16(v.z); p.w = f32_to_bf16(v.w);
      prow[q4] = p;
    }
  }
}

// ---------------- att_output = P @ v (vT layout), causal K truncation ----------------
__global__ __launch_bounds__(256) void k_pv(const u16* __restrict__ P,
                                            const u16* __restrict__ vT,
                                            float* __restrict__ out) {
  const int id = blockIdx.x;               // [0,512)
  const int mt = 15 - (id >> 5);           // [0,16), descending K (LPT)
  const int nt = (id >> 2) & 7;            // [0,8)
  const int b = id & 3;                    // [0,4)
  __shared__ u16 lds[32768];
  floatx4 acc[4][4] = {};
  mfma_core128(P + (size_t)b * SEQ * SEQ + (size_t)mt * 128 * SEQ, SEQ,
               vT + (size_t)b * DIM * SEQ + (size_t)nt * 128 * SEQ, SEQ,
               mt + 1, lds, acc);
  const int lane = threadIdx.x & 63, wid = threadIdx.x >> 6;
  const int wm = (wid >> 1) * 64, wn = (wid & 1) * 64;
  const int lrow = lane & 15, quad = lane >> 4;
  float* C = out + (size_t)b * SEQ * DIM
                 + (size_t)(mt * 128 + wm + quad * 4) * DIM + nt * 128 + wn + lrow;
  #pragma unroll
  for (int i = 0; i < 4; ++i)
    #pragma unroll
    for (int rr = 0; rr < 4; ++rr)
      #pragma unroll
      for (int j = 0; j < 4; ++j)
        C[(size_t)(i * 16 + rr) * DIM + j * 16] = acc[i][j][rr];
}

extern "C" void kernel_launch(void* const* d_in, const int* in_sizes, int n_in,
                              void* d_out, int out_size, void* d_ws, size_t ws_size,
                              hipStream_t stream) {
  const float* x  = (const float*)d_in[0];
  const float* Wq = (const float*)d_in[1];
  const float* Wk = (const float*)d_in[2];
  const float* Wv = (const float*)d_in[3];
  float* att_out = (float*)d_out;                    // [4,2048,1024]
  float* att_w   = (float*)d_out + 8388608;          // [4,2048,2048]

  // workspace layout (bf16 elements); ~107 MB
  u16* xb = (u16*)d_ws;             // 8,388,608   x bf16
  u16* wt = xb + 8388608;           // 3,145,728   Wq^T,Wk^T,Wv^T bf16
  u16* qk = wt + 3145728;           // 16,777,216  q,k bf16
  u16* vT = qk + 16777216;          // 8,388,608   v^T per batch
  u16* P  = vT + 8388608;           // 16,777,216  softmax probs bf16

  k_prep<<<7168, 256, 0, stream>>>(x, Wq, Wk, Wv, xb, wt);
  k_proj8<<<384, 512, 0, stream>>>(xb, wt, qk, vT);
  k_scores<<<544, 256, 0, stream>>>(qk, qk + 8388608, att_w);
  k_softmax<<<8192, 256, 0, stream>>>(att_w, P);
  k_pv<<<512, 256, 0, stream>>>(P, vT, att_out);
}

// Round 5
// 268.360 us; speedup vs baseline: 1.0144x; 1.0144x over previous
//
#include <hip/hip_runtime.h>
#include <stdint.h>

#define DIM 1024
#define SEQ 2048
#define NB 4

typedef unsigned short u16;
typedef __bf16 bf16x8 __attribute__((ext_vector_type(8)));
typedef float floatx4 __attribute__((ext_vector_type(4)));

__device__ __forceinline__ u16 f32_to_bf16(float f) {
  union { float f; unsigned u; } v; v.f = f;
  unsigned r = v.u + 0x7FFFu + ((v.u >> 16) & 1u);
  return (u16)(r >> 16);
}

__device__ __forceinline__ void async16(const void* g, void* l) {
  __builtin_amdgcn_global_load_lds(
      (__attribute__((address_space(1))) unsigned int*)g,
      (__attribute__((address_space(3))) unsigned int*)l, 16, 0, 0);
}

// ---------------- prep: x fp32->bf16 (16B stores)  +  W transpose ----------------
__global__ __launch_bounds__(256) void k_prep(const float* __restrict__ x,
                                              const float* __restrict__ Wq,
                                              const float* __restrict__ Wk,
                                              const float* __restrict__ Wv,
                                              u16* __restrict__ xb,
                                              u16* __restrict__ wt) {
  __shared__ u16 tile[32][33];
  const int bid = blockIdx.x;
  const int tid = threadIdx.x;
  if (bid < 4096) {                       // cvt: 4096 blocks x 256 x 8 floats
    int i = bid * 256 + tid;
    float4 a = ((const float4*)x)[i * 2];
    float4 b = ((const float4*)x)[i * 2 + 1];
    ushort4 o0, o1;
    o0.x = f32_to_bf16(a.x); o0.y = f32_to_bf16(a.y);
    o0.z = f32_to_bf16(a.z); o0.w = f32_to_bf16(a.w);
    o1.x = f32_to_bf16(b.x); o1.y = f32_to_bf16(b.y);
    o1.z = f32_to_bf16(b.z); o1.w = f32_to_bf16(b.w);
    ((ushort4*)xb)[i * 2] = o0;
    ((ushort4*)xb)[i * 2 + 1] = o1;
  } else {                                // transpose: 3 x 1024 tile-blocks
    int t = bid - 4096;
    int z = t >> 10;
    int ti = t & 1023;
    int c0 = (ti & 31) * 32, r0 = (ti >> 5) * 32;
    const float* src = (z == 0) ? Wq : (z == 1) ? Wk : Wv;
    u16* d = wt + (size_t)z * DIM * DIM;
    int tx = tid & 31, ty = tid >> 5;     // 32 x 8
    #pragma unroll
    for (int dy = 0; dy < 32; dy += 8)
      tile[ty + dy][tx] = f32_to_bf16(src[(size_t)(r0 + ty + dy) * DIM + c0 + tx]);
    __syncthreads();
    #pragma unroll
    for (int dy = 0; dy < 32; dy += 8)
      d[(size_t)(c0 + ty + dy) * DIM + r0 + tx] = tile[tx][ty + dy];
  }
}

// ============ 8-phase 256x256 GEMM core, m201-exact fencing ============
// 8 waves (2Mx4N), BK=64, 2 K-tiles/iteration across 8 phases.
// LDS = 4 slots of one K-tile each: A0 | A1 | B0 | B1 (32 KB each, 128 KB).
// Round-2 stage spread (1 pair/phase), counted vmcnt(2) at ph2/ph6.
// Fencing per verified m201 template: NO "memory" clobbers, NO per-phase
// sched_barrier(0) (m141: order-pinning every phase = 510 TF). sched_barrier
// only after the two counted vmcnt syncs (protects DMA->ds_read RAW).

#define STG(PG, STBASE, SLOT, H, I, KT)                                        \
  async16((PG) + (size_t)((H) * 128 + (I) * 64) * DIM + (KT) * 64,             \
          (STBASE) + (SLOT) * 16384 + (H) * 8192 + (I) * 4096)

#define PHASE(SLOT, KS, MH, RDB, STGS, SYNC)                                   \
  {                                                                            \
    const int go_ = (KS) ? ga1 : ga0;                                          \
    const u16* pa_ = aRd + (SLOT) * 16384;                                     \
    if (RDB) {                                                                 \
      const u16* pb_ = bRd + (SLOT) * 16384;                                   \
      _Pragma("unroll") for (int n = 0; n < 4; ++n)                            \
          bfr[n] = *(const bf16x8*)(pb_ + n * 1024 + go_);                     \
    }                                                                          \
    _Pragma("unroll") for (int m = 0; m < 4; ++m)                              \
        af[m] = *(const bf16x8*)(pa_ + ((MH) * 4 + m) * 1024 + go_);           \
    STGS                                                                       \
    __builtin_amdgcn_s_barrier();                                              \
    asm volatile("s_waitcnt lgkmcnt(0)");                                      \
    __builtin_amdgcn_s_setprio(1);                                             \
    _Pragma("unroll") for (int m = 0; m < 4; ++m)                              \
        _Pragma("unroll") for (int n = 0; n < 4; ++n)                          \
            acc[(MH) * 4 + m][n] = __builtin_amdgcn_mfma_f32_16x16x32_bf16(    \
                af[m], bfr[n], acc[(MH) * 4 + m][n], 0, 0, 0);                 \
    __builtin_amdgcn_s_setprio(0);                                             \
    SYNC                                                                       \
    __builtin_amdgcn_s_barrier();                                              \
  }

// jobs: [0,128) q tiles, [128,256) k tiles, [256,384) vT tiles. 384%8==0 so the
// simple XCD swizzle is bijective; each XCD gets 48 consecutive tile ids.
__global__ __launch_bounds__(512) void k_proj8(const u16* __restrict__ xb,
                                               const u16* __restrict__ wt,
                                               u16* __restrict__ qk,
                                               u16* __restrict__ vT) {
  __shared__ u16 lds[65536];               // 128 KB: A0|A1|B0|B1
  const int wg = ((blockIdx.x & 7) * 48) + (blockIdx.x >> 3);
  const int tid = threadIdx.x;
  const int lane = tid & 63;
  const int wid = tid >> 6;

  const u16 *A, *Bt;
  u16* Cout;
  int ldc;
  if (wg < 256) {
    const int z = wg >> 7;                 // 0=q, 1=k
    const int r = wg & 127;
    const int mt = r >> 2, nt = r & 3;     // 32 x 4 tiles of 256x256
    A = xb + (size_t)mt * 256 * DIM;
    Bt = wt + (size_t)z * DIM * DIM + (size_t)nt * 256 * DIM;
    Cout = qk + (size_t)z * (NB * SEQ * DIM) + (size_t)mt * 256 * DIM + nt * 256;
    ldc = DIM;
  } else {                                 // vT = Wv^T @ x^T
    const int r = wg - 256;
    const int mt = r & 3, nt = r >> 2;     // mt inner: 4 blocks sharing an xb
                                           // panel are XCD-adjacent (L2 fix,
                                           // FETCH 62->42 MB verified r4)
    A = wt + (size_t)2 * DIM * DIM + (size_t)mt * 256 * DIM;
    Bt = xb + (size_t)nt * 256 * DIM;
    Cout = vT + (size_t)(nt >> 3) * (DIM * SEQ) + (size_t)mt * 256 * SEQ
              + (nt & 7) * 256;
    ldc = SEQ;
  }

  // staging: per issue, wave covers 8 rows x 8 granules; pre-swizzled source.
  const int srow = wid * 8 + (lane >> 3);
  const int gsrc = (lane & 7) ^ ((lane >> 3) & 7);
  const u16* pga = A + (size_t)srow * DIM + gsrc * 8;
  const u16* pgb = Bt + (size_t)srow * DIM + gsrc * 8;
  u16* stA = lds + wid * 512;              // wave-uniform LDS dest bases
  u16* stB = lds + 32768 + wid * 512;

  // compute-side addressing
  const int wr = wid >> 2, wc = wid & 3;
  const int lrow = lane & 15, quad = lane >> 4;
  const int s = lrow & 7;
  const u16* aRd = lds + (wr * 128 + lrow) * 64;
  const u16* bRd = lds + 32768 + (wc * 64 + lrow) * 64;
  const int ga0 = (quad ^ s) << 3;         // ksub0 granule (u16 offset)
  const int ga1 = ga0 ^ 32;                // ksub1

  floatx4 acc[8][4] = {};
  bf16x8 af[4], bfr[4];

  // prologue: K0 -> A0,B0 (8 issues), K1 -> B1 half0 (2 issues)
  STG(pga, stA, 0, 0, 0, 0); STG(pga, stA, 0, 0, 1, 0);
  STG(pga, stA, 0, 1, 0, 0); STG(pga, stA, 0, 1, 1, 0);
  STG(pgb, stB, 0, 0, 0, 0); STG(pgb, stB, 0, 0, 1, 0);
  STG(pgb, stB, 0, 1, 0, 0); STG(pgb, stB, 0, 1, 1, 0);
  STG(pgb, stB, 1, 0, 0, 1); STG(pgb, stB, 1, 0, 1, 1);
  asm volatile("s_waitcnt vmcnt(2)");
  __builtin_amdgcn_sched_barrier(0);
  __builtin_amdgcn_s_barrier();

  const int NITER = DIM / 128;             // 8 iterations, 2 K-tiles each
  for (int t = 0; t < NITER; ++t) {
    const bool more = (t + 1 < NITER);
    const int kA1 = 2 * t + 1;             // slot1 content consumed this iter
    const int kN = 2 * t + 2;              // next slot0 content
    const int kB1n = 2 * t + 3;            // next slot1 B half0

    // ph0: slot0 ks0 mh0 (reads B0); stage A1 h0 <- kA1
    PHASE(0, 0, 0, 1,
          { STG(pga, stA, 1, 0, 0, kA1); STG(pga, stA, 1, 0, 1, kA1); }, {})
    // ph1: slot0 ks0 mh1; stage A1 h1
    PHASE(0, 0, 1, 0,
          { STG(pga, stA, 1, 1, 0, kA1); STG(pga, stA, 1, 1, 1, kA1); }, {})
    // ph2: slot0 ks1 mh0 (reads B0 ks1); stage B1 h1 <- kA1
    PHASE(0, 1, 0, 1,
          { STG(pgb, stB, 1, 1, 0, kA1); STG(pgb, stB, 1, 1, 1, kA1); }, {})
    // ph3: slot0 ks1 mh1; stage B0 h0 <- kN; MID-SYNC (slot1 data landed)
    PHASE(0, 1, 1, 0,
          { if (more) { STG(pgb, stB, 0, 0, 0, kN); STG(pgb, stB, 0, 0, 1, kN); } },
          { if (more) { asm volatile("s_waitcnt vmcnt(2)"); }
            else      { asm volatile("s_waitcnt vmcnt(0)"); }
            __builtin_amdgcn_sched_barrier(0); })
    // ph4: slot1 ks0 mh0 (reads B1); stage B0 h1 <- kN
    PHASE(1, 0, 0, 1,
          { if (more) { STG(pgb, stB, 0, 1, 0, kN); STG(pgb, stB, 0, 1, 1, kN); } }, {})
    // ph5: slot1 ks0 mh1; stage A0 h0 <- kN
    PHASE(1, 0, 1, 0,
          { if (more) { STG(pga, stA, 0, 0, 0, kN); STG(pga, stA, 0, 0, 1, kN); } }, {})
    // ph6: slot1 ks1 mh0 (reads B1 ks1); stage A0 h1 <- kN
    PHASE(1, 1, 0, 1,
          { if (more) { STG(pga, stA, 0, 1, 0, kN); STG(pga, stA, 0, 1, 1, kN); } }, {})
    // ph7: slot1 ks1 mh1; stage B1 h0 <- kB1n; END-SYNC (slot0 data landed)
    PHASE(1, 1, 1, 0,
          { if (more) { STG(pgb, stB, 1, 0, 0, kB1n); STG(pgb, stB, 1, 0, 1, kB1n); } },
          { if (more) { asm volatile("s_waitcnt vmcnt(2)");
                        __builtin_amdgcn_sched_barrier(0); } })
  }

  // insurance: ledger says vmcnt==0 here; free if so.
  asm volatile("s_waitcnt vmcnt(0)");

  // epilogue: row = wr*128 + m*16 + quad*4 + rr, col = wc*64 + n*16 + lrow
  u16* C = Cout + (size_t)(wr * 128 + quad * 4) * ldc + wc * 64 + lrow;
  #pragma unroll
  for (int m = 0; m < 8; ++m)
    #pragma unroll
    for (int rr = 0; rr < 4; ++rr)
      #pragma unroll
      for (int n = 0; n < 4; ++n)
        C[(size_t)(m * 16 + rr) * ldc + n * 16] = f32_to_bf16(acc[m][n][rr]);
}

// ---------------- BK=128 MFMA core (scores/pv: grid-capped residency) ----------------
__device__ __forceinline__ void mfma_core128(const u16* __restrict__ A, int lda,
                                             const u16* __restrict__ Bt, int ldb,
                                             int kchunks, u16* lds,
                                             floatx4 acc[4][4]) {
  const int tid = threadIdx.x;
  const int lane = tid & 63;
  const int wid = tid >> 6;
  u16* lds_a = lds;            // 128 x 128 (swizzled granules)
  u16* lds_b = lds + 16384;

  const int srow4 = lane >> 4;          // 0..3
  const int sgr = lane & 15;
  const int gbase = sgr ^ srow4;        // even c
  const u16* ag0 = A + (size_t)(wid * 32 + srow4) * lda + gbase * 8;
  const u16* ag1 = A + (size_t)(wid * 32 + srow4) * lda + (gbase ^ 4) * 8;
  const u16* bg0 = Bt + (size_t)(wid * 32 + srow4) * ldb + gbase * 8;
  const u16* bg1 = Bt + (size_t)(wid * 32 + srow4) * ldb + (gbase ^ 4) * 8;
  u16* la = lds_a + wid * 4096;         // 32 rows x 128
  u16* lb = lds_b + wid * 4096;

  const int wm = (wid >> 1) * 64, wn = (wid & 1) * 64;
  const int lrow = lane & 15, quad = lane >> 4;
  const int s = lrow & 7;
  const u16* pa = lds_a + (wm + lrow) * 128;
  const u16* pb = lds_b + (wn + lrow) * 128;

  for (int kt = 0; kt < kchunks; ++kt) {
    #pragma unroll
    for (int c = 0; c < 8; ++c) {
      const u16* sa = ((c & 1) ? ag1 : ag0) + (size_t)(c * 4) * lda;
      async16(sa, la + c * 512);
    }
    #pragma unroll
    for (int c = 0; c < 8; ++c) {
      const u16* sb = ((c & 1) ? bg1 : bg0) + (size_t)(c * 4) * ldb;
      async16(sb, lb + c * 512);
    }
    ag0 += 128; ag1 += 128; bg0 += 128; bg1 += 128;
    __syncthreads();
    #pragma unroll
    for (int ks = 0; ks < 4; ++ks) {
      const int g = (((ks << 2) | quad) ^ s) << 3;
      bf16x8 af[4], bfr[4];
      #pragma unroll
      for (int t = 0; t < 4; ++t) af[t] = *(const bf16x8*)(pa + t * 2048 + g);
      #pragma unroll
      for (int t = 0; t < 4; ++t) bfr[t] = *(const bf16x8*)(pb + t * 2048 + g);
      #pragma unroll
      for (int i = 0; i < 4; ++i)
        #pragma unroll
        for (int j = 0; j < 4; ++j)
          acc[i][j] = __builtin_amdgcn_mfma_f32_16x16x32_bf16(af[i], bfr[j],
                                                              acc[i][j], 0, 0, 0);
    }
    __syncthreads();
  }
}

// ---------------- scores = (q @ k^T) * scale, exact lower-triangle grid ----------------
__global__ __launch_bounds__(256) void k_scores(const u16* __restrict__ q,
                                                const u16* __restrict__ k,
                                                float* __restrict__ w) {
  const int id = blockIdx.x;               // [0,544)
  const int b = id & 3;
  int t = id >> 2;                         // [0,136)
  int mt = (int)((sqrtf(8.0f * (float)t + 1.0f) - 1.0f) * 0.5f);
  while ((mt + 1) * (mt + 2) / 2 <= t) ++mt;
  while (mt * (mt + 1) / 2 > t) --mt;
  const int nt = t - mt * (mt + 1) / 2;
  __shared__ u16 lds[32768];
  floatx4 acc[4][4] = {};
  mfma_core128(q + (size_t)b * SEQ * DIM + (size_t)mt * 128 * DIM, DIM,
               k + (size_t)b * SEQ * DIM + (size_t)nt * 128 * DIM, DIM,
               DIM / 128, lds, acc);
  const int lane = threadIdx.x & 63, wid = threadIdx.x >> 6;
  const int wm = (wid >> 1) * 64, wn = (wid & 1) * 64;
  const int lrow = lane & 15, quad = lane >> 4;
  float* C = w + (size_t)b * SEQ * SEQ
               + (size_t)(mt * 128 + wm + quad * 4) * SEQ + nt * 128 + wn + lrow;
  #pragma unroll
  for (int i = 0; i < 4; ++i)
    #pragma unroll
    for (int rr = 0; rr < 4; ++rr)
      #pragma unroll
      for (int j = 0; j < 4; ++j)
        C[(size_t)(i * 16 + rr) * SEQ + j * 16] = acc[i][j][rr] * 0.03125f;
}

// ---------------- row softmax: weights fp32 (in-place) + P bf16 ----------------
__global__ __launch_bounds__(256) void k_softmax(float* __restrict__ w,
                                                 u16* __restrict__ P) {
  const int r = blockIdx.x;
  const int i = r & (SEQ - 1);
  const int len = i + 1;
  const int plen4 = (((i >> 7) + 1) << 7) >> 2;   // P write bound / float4
  float4* srow = (float4*)(w + (size_t)r * SEQ);
  ushort4* prow = (ushort4*)(P + (size_t)r * SEQ);
  const int tid = threadIdx.x;
  const int lane = tid & 63, wid = tid >> 6;
  __shared__ float rm[4], rs[4];

  float4 e[2];
  float mx = -1e30f;
  #pragma unroll
  for (int u = 0; u < 2; ++u) {
    int q4 = tid + u * 256;
    int j0 = q4 * 4;
    float4 v = make_float4(-1e30f, -1e30f, -1e30f, -1e30f);
    if (j0 < len) {
      v = srow[q4];
      v.x = (j0 + 0 < len) ? v.x : -1e30f;
      v.y = (j0 + 1 < len) ? v.y : -1e30f;
      v.z = (j0 + 2 < len) ? v.z : -1e30f;
      v.w = (j0 + 3 < len) ? v.w : -1e30f;
    }
    e[u] = v;
    mx = fmaxf(mx, fmaxf(fmaxf(v.x, v.y), fmaxf(v.z, v.w)));
  }
  #pragma unroll
  for (int o = 32; o >= 1; o >>= 1) mx = fmaxf(mx, __shfl_xor(mx, o, 64));
  if (lane == 0) rm[wid] = mx;
  __syncthreads();
  mx = fmaxf(fmaxf(rm[0], rm[1]), fmaxf(rm[2], rm[3]));

  float sum = 0.f;
  #pragma unroll
  for (int u = 0; u < 2; ++u) {
    e[u].x = __expf(e[u].x - mx);
    e[u].y = __expf(e[u].y - mx);
    e[u].z = __expf(e[u].z - mx);
    e[u].w = __expf(e[u].w - mx);
    sum += e[u].x + e[u].y + e[u].z + e[u].w;
  }
  #pragma unroll
  for (int o = 32; o >= 1; o >>= 1) sum += __shfl_xor(sum, o, 64);
  if (lane == 0) rs[wid] = sum;
  __syncthreads();
  sum = rs[0] + rs[1] + rs[2] + rs[3];
  const float inv = 1.0f / sum;

  #pragma unroll
  for (int u = 0; u < 2; ++u) {
    int q4 = tid + u * 256;
    int j0 = q4 * 4;
    float4 v;
    v.x = (j0 + 0 < len) ? e[u].x * inv : 0.f;
    v.y = (j0 + 1 < len) ? e[u].y * inv : 0.f;
    v.z = (j0 + 2 < len) ? e[u].z * inv : 0.f;
    v.w = (j0 + 3 < len) ? e[u].w * inv : 0.f;
    srow[q4] = v;                   // full fp32 row incl. zeros (output!)
    if (q4 < plen4) {
      ushort4 p;
      p.x = f32_to_bf16(v.x); p.y = f32_to_bf16(v.y);
      p.z = f32_to_bf16(v.z); p.w = f32_to_bf16(v.w);
      prow[q4] = p;
    }
  }
}

// ---------------- att_output = P @ v (vT layout), causal K truncation ----------------
__global__ __launch_bounds__(256) void k_pv(const u16* __restrict__ P,
                                            const u16* __restrict__ vT,
                                            float* __restrict__ out) {
  const int id = blockIdx.x;               // [0,512)
  const int mt = 15 - (id >> 5);           // [0,16), descending K (LPT)
  const int nt = (id >> 2) & 7;            // [0,8)
  const int b = id & 3;                    // [0,4)
  __shared__ u16 lds[32768];
  floatx4 acc[4][4] = {};
  mfma_core128(P + (size_t)b * SEQ * SEQ + (size_t)mt * 128 * SEQ, SEQ,
               vT + (size_t)b * DIM * SEQ + (size_t)nt * 128 * SEQ, SEQ,
               mt + 1, lds, acc);
  const int lane = threadIdx.x & 63, wid = threadIdx.x >> 6;
  const int wm = (wid >> 1) * 64, wn = (wid & 1) * 64;
  const int lrow = lane & 15, quad = lane >> 4;
  float* C = out + (size_t)b * SEQ * DIM
                 + (size_t)(mt * 128 + wm + quad * 4) * DIM + nt * 128 + wn + lrow;
  #pragma unroll
  for (int i = 0; i < 4; ++i)
    #pragma unroll
    for (int rr = 0; rr < 4; ++rr)
      #pragma unroll
      for (int j = 0; j < 4; ++j)
        C[(size_t)(i * 16 + rr) * DIM + j * 16] = acc[i][j][rr];
}

extern "C" void kernel_launch(void* const* d_in, const int* in_sizes, int n_in,
                              void* d_out, int out_size, void* d_ws, size_t ws_size,
                              hipStream_t stream) {
  const float* x  = (const float*)d_in[0];
  const float* Wq = (const float*)d_in[1];
  const float* Wk = (const float*)d_in[2];
  const float* Wv = (const float*)d_in[3];
  float* att_out = (float*)d_out;                    // [4,2048,1024]
  float* att_w   = (float*)d_out + 8388608;          // [4,2048,2048]

  // workspace layout (bf16 elements); ~107 MB
  u16* xb = (u16*)d_ws;             // 8,388,608   x bf16
  u16* wt = xb + 8388608;           // 3,145,728   Wq^T,Wk^T,Wv^T bf16
  u16* qk = wt + 3145728;           // 16,777,216  q,k bf16
  u16* vT = qk + 16777216;          // 8,388,608   v^T per batch
  u16* P  = vT + 8388608;           // 16,777,216  softmax probs bf16

  k_prep<<<7168, 256, 0, stream>>>(x, Wq, Wk, Wv, xb, wt);
  k_proj8<<<384, 512, 0, stream>>>(xb, wt, qk, vT);
  k_scores<<<544, 256, 0, stream>>>(qk, qk + 8388608, att_w);
  k_softmax<<<8192, 256, 0, stream>>>(att_w, P);
  k_pv<<<512, 256, 0, stream>>>(P, vT, att_out);
}

// Round 6
// 265.485 us; speedup vs baseline: 1.0254x; 1.0108x over previous
//
#include <hip/hip_runtime.h>
#include <stdint.h>

#define DIM 1024
#define SEQ 2048
#define NB 4

typedef unsigned short u16;
typedef __bf16 bf16x8 __attribute__((ext_vector_type(8)));
typedef float floatx4 __attribute__((ext_vector_type(4)));

__device__ __forceinline__ u16 f32_to_bf16(float f) {
  union { float f; unsigned u; } v; v.f = f;
  unsigned r = v.u + 0x7FFFu + ((v.u >> 16) & 1u);
  return (u16)(r >> 16);
}

__device__ __forceinline__ void async16(const void* g, void* l) {
  __builtin_amdgcn_global_load_lds(
      (__attribute__((address_space(1))) unsigned int*)g,
      (__attribute__((address_space(3))) unsigned int*)l, 16, 0, 0);
}

// ---------------- prep: x fp32->bf16 (16B stores)  +  W transpose ----------------
__global__ __launch_bounds__(256) void k_prep(const float* __restrict__ x,
                                              const float* __restrict__ Wq,
                                              const float* __restrict__ Wk,
                                              const float* __restrict__ Wv,
                                              u16* __restrict__ xb,
                                              u16* __restrict__ wt) {
  __shared__ u16 tile[32][33];
  const int bid = blockIdx.x;
  const int tid = threadIdx.x;
  if (bid < 4096) {                       // cvt: 4096 blocks x 256 x 8 floats
    int i = bid * 256 + tid;
    float4 a = ((const float4*)x)[i * 2];
    float4 b = ((const float4*)x)[i * 2 + 1];
    ushort4 o0, o1;
    o0.x = f32_to_bf16(a.x); o0.y = f32_to_bf16(a.y);
    o0.z = f32_to_bf16(a.z); o0.w = f32_to_bf16(a.w);
    o1.x = f32_to_bf16(b.x); o1.y = f32_to_bf16(b.y);
    o1.z = f32_to_bf16(b.z); o1.w = f32_to_bf16(b.w);
    ((ushort4*)xb)[i * 2] = o0;
    ((ushort4*)xb)[i * 2 + 1] = o1;
  } else {                                // transpose: 3 x 1024 tile-blocks
    int t = bid - 4096;
    int z = t >> 10;
    int ti = t & 1023;
    int c0 = (ti & 31) * 32, r0 = (ti >> 5) * 32;
    const float* src = (z == 0) ? Wq : (z == 1) ? Wk : Wv;
    u16* d = wt + (size_t)z * DIM * DIM;
    int tx = tid & 31, ty = tid >> 5;     // 32 x 8
    #pragma unroll
    for (int dy = 0; dy < 32; dy += 8)
      tile[ty + dy][tx] = f32_to_bf16(src[(size_t)(r0 + ty + dy) * DIM + c0 + tx]);
    __syncthreads();
    #pragma unroll
    for (int dy = 0; dy < 32; dy += 8)
      d[(size_t)(c0 + ty + dy) * DIM + r0 + tx] = tile[tx][ty + dy];
  }
}

// ============ shared 8-phase 256x256 GEMM core (both operands stride DIM) ============
// 8 waves (2Mx4N), BK=64, 2 K-tiles/iteration across 8 phases.
// LDS = 4 slots of one K-tile each: A0 | A1 | B0 | B1 (32 KB each, 128 KB).
// Counted vmcnt(2) at ph3/ph7 mids; vmcnt(0) only on final drain.

#define STG(PG, STBASE, SLOT, H, I, KT)                                        \
  async16((PG) + (size_t)((H) * 128 + (I) * 64) * DIM + (KT) * 64,             \
          (STBASE) + (SLOT) * 16384 + (H) * 8192 + (I) * 4096)

#define PHASE(SLOT, KS, MH, RDB, STGS, SYNC)                                   \
  {                                                                            \
    const int go_ = (KS) ? ga1 : ga0;                                          \
    const u16* pa_ = aRd + (SLOT) * 16384;                                     \
    if (RDB) {                                                                 \
      const u16* pb_ = bRd + (SLOT) * 16384;                                   \
      _Pragma("unroll") for (int n = 0; n < 4; ++n)                            \
          bfr[n] = *(const bf16x8*)(pb_ + n * 1024 + go_);                     \
    }                                                                          \
    _Pragma("unroll") for (int m = 0; m < 4; ++m)                              \
        af[m] = *(const bf16x8*)(pa_ + ((MH) * 4 + m) * 1024 + go_);           \
    STGS                                                                       \
    __builtin_amdgcn_s_barrier();                                              \
    asm volatile("s_waitcnt lgkmcnt(0)");                                      \
    __builtin_amdgcn_s_setprio(1);                                             \
    _Pragma("unroll") for (int m = 0; m < 4; ++m)                              \
        _Pragma("unroll") for (int n = 0; n < 4; ++n)                          \
            acc[(MH) * 4 + m][n] = __builtin_amdgcn_mfma_f32_16x16x32_bf16(    \
                af[m], bfr[n], acc[(MH) * 4 + m][n], 0, 0, 0);                 \
    __builtin_amdgcn_s_setprio(0);                                             \
    SYNC                                                                       \
    __builtin_amdgcn_s_barrier();                                              \
  }

__device__ __forceinline__ void core256(const u16* __restrict__ pga,
                                        const u16* __restrict__ pgb,
                                        const u16* aRd, const u16* bRd,
                                        u16* stA, u16* stB,
                                        int ga0, int ga1,
                                        floatx4 acc[8][4], int NITER) {
  bf16x8 af[4], bfr[4];

  // prologue: K0 -> A0,B0 (8 issues), K1 -> B1 half0 (2 issues)
  STG(pga, stA, 0, 0, 0, 0); STG(pga, stA, 0, 0, 1, 0);
  STG(pga, stA, 0, 1, 0, 0); STG(pga, stA, 0, 1, 1, 0);
  STG(pgb, stB, 0, 0, 0, 0); STG(pgb, stB, 0, 0, 1, 0);
  STG(pgb, stB, 0, 1, 0, 0); STG(pgb, stB, 0, 1, 1, 0);
  STG(pgb, stB, 1, 0, 0, 1); STG(pgb, stB, 1, 0, 1, 1);
  asm volatile("s_waitcnt vmcnt(2)");
  __builtin_amdgcn_sched_barrier(0);
  __builtin_amdgcn_s_barrier();

  for (int t = 0; t < NITER; ++t) {
    const bool more = (t + 1 < NITER);
    const int kA1 = 2 * t + 1;             // slot1 content consumed this iter
    const int kN = 2 * t + 2;              // next slot0 content
    const int kB1n = 2 * t + 3;            // next slot1 B half0

    // ph0: slot0 ks0 mh0 (reads B0); stage A1 h0 <- kA1
    PHASE(0, 0, 0, 1,
          { STG(pga, stA, 1, 0, 0, kA1); STG(pga, stA, 1, 0, 1, kA1); }, {})
    // ph1: slot0 ks0 mh1; stage A1 h1
    PHASE(0, 0, 1, 0,
          { STG(pga, stA, 1, 1, 0, kA1); STG(pga, stA, 1, 1, 1, kA1); }, {})
    // ph2: slot0 ks1 mh0 (reads B0 ks1); stage B1 h1 <- kA1
    PHASE(0, 1, 0, 1,
          { STG(pgb, stB, 1, 1, 0, kA1); STG(pgb, stB, 1, 1, 1, kA1); }, {})
    // ph3: slot0 ks1 mh1; stage B0 h0 <- kN; MID-SYNC (slot1 data landed)
    PHASE(0, 1, 1, 0,
          { if (more) { STG(pgb, stB, 0, 0, 0, kN); STG(pgb, stB, 0, 0, 1, kN); } },
          { if (more) { asm volatile("s_waitcnt vmcnt(2)"); }
            else      { asm volatile("s_waitcnt vmcnt(0)"); }
            __builtin_amdgcn_sched_barrier(0); })
    // ph4: slot1 ks0 mh0 (reads B1); stage B0 h1 <- kN
    PHASE(1, 0, 0, 1,
          { if (more) { STG(pgb, stB, 0, 1, 0, kN); STG(pgb, stB, 0, 1, 1, kN); } }, {})
    // ph5: slot1 ks0 mh1; stage A0 h0 <- kN
    PHASE(1, 0, 1, 0,
          { if (more) { STG(pga, stA, 0, 0, 0, kN); STG(pga, stA, 0, 0, 1, kN); } }, {})
    // ph6: slot1 ks1 mh0 (reads B1 ks1); stage A0 h1 <- kN
    PHASE(1, 1, 0, 1,
          { if (more) { STG(pga, stA, 0, 1, 0, kN); STG(pga, stA, 0, 1, 1, kN); } }, {})
    // ph7: slot1 ks1 mh1; stage B1 h0 <- kB1n; END-SYNC (slot0 data landed)
    PHASE(1, 1, 1, 0,
          { if (more) { STG(pgb, stB, 1, 0, 0, kB1n); STG(pgb, stB, 1, 0, 1, kB1n); } },
          { if (more) { asm volatile("s_waitcnt vmcnt(2)");
                        __builtin_amdgcn_sched_barrier(0); } })
  }

  // drain: ledger says vmcnt==0 here; free if so.
  asm volatile("s_waitcnt vmcnt(0)");
}

// jobs: [0,128) q tiles, [128,256) k tiles, [256,384) vT tiles. 384%8==0 so the
// simple XCD swizzle is bijective; each XCD gets 48 consecutive tile ids.
__global__ __launch_bounds__(512) void k_proj8(const u16* __restrict__ xb,
                                               const u16* __restrict__ wt,
                                               u16* __restrict__ qk,
                                               u16* __restrict__ vT) {
  __shared__ u16 lds[65536];               // 128 KB: A0|A1|B0|B1
  const int wg = ((blockIdx.x & 7) * 48) + (blockIdx.x >> 3);
  const int tid = threadIdx.x;
  const int lane = tid & 63;
  const int wid = tid >> 6;

  const u16 *A, *Bt;
  u16* Cout;
  int ldc;
  if (wg < 256) {
    const int z = wg >> 7;                 // 0=q, 1=k
    const int r = wg & 127;
    const int mt = r >> 2, nt = r & 3;     // 32 x 4 tiles of 256x256
    A = xb + (size_t)mt * 256 * DIM;
    Bt = wt + (size_t)z * DIM * DIM + (size_t)nt * 256 * DIM;
    Cout = qk + (size_t)z * (NB * SEQ * DIM) + (size_t)mt * 256 * DIM + nt * 256;
    ldc = DIM;
  } else {                                 // vT = Wv^T @ x^T
    const int r = wg - 256;
    const int mt = r & 3, nt = r >> 2;     // mt inner: 4 blocks sharing an xb
                                           // panel are XCD-adjacent (L2 fix,
                                           // FETCH 62->42 MB verified r4)
    A = wt + (size_t)2 * DIM * DIM + (size_t)mt * 256 * DIM;
    Bt = xb + (size_t)nt * 256 * DIM;
    Cout = vT + (size_t)(nt >> 3) * (DIM * SEQ) + (size_t)mt * 256 * SEQ
              + (nt & 7) * 256;
    ldc = SEQ;
  }

  // staging: per issue, wave covers 8 rows x 8 granules; pre-swizzled source.
  const int srow = wid * 8 + (lane >> 3);
  const int gsrc = (lane & 7) ^ ((lane >> 3) & 7);
  const u16* pga = A + (size_t)srow * DIM + gsrc * 8;
  const u16* pgb = Bt + (size_t)srow * DIM + gsrc * 8;
  u16* stA = lds + wid * 512;              // wave-uniform LDS dest bases
  u16* stB = lds + 32768 + wid * 512;

  // compute-side addressing
  const int wr = wid >> 2, wc = wid & 3;
  const int lrow = lane & 15, quad = lane >> 4;
  const int s = lrow & 7;
  const u16* aRd = lds + (wr * 128 + lrow) * 64;
  const u16* bRd = lds + 32768 + (wc * 64 + lrow) * 64;
  const int ga0 = (quad ^ s) << 3;         // ksub0 granule (u16 offset)
  const int ga1 = ga0 ^ 32;                // ksub1

  floatx4 acc[8][4] = {};
  core256(pga, pgb, aRd, bRd, stA, stB, ga0, ga1, acc, DIM / 128);

  // epilogue: row = wr*128 + m*16 + quad*4 + rr, col = wc*64 + n*16 + lrow
  u16* C = Cout + (size_t)(wr * 128 + quad * 4) * ldc + wc * 64 + lrow;
  #pragma unroll
  for (int m = 0; m < 8; ++m)
    #pragma unroll
    for (int rr = 0; rr < 4; ++rr)
      #pragma unroll
      for (int n = 0; n < 4; ++n)
        C[(size_t)(m * 16 + rr) * ldc + n * 16] = f32_to_bf16(acc[m][n][rr]);
}

// ---------------- scores = (q @ k^T) * scale, 256^2 tiles, triangular grid ----------------
// 36 triangular 256-tiles x 4 batches = 144 blocks (18 per XCD, bijective).
// Diagonal tiles compute their upper-128 halves harmlessly (softmax overwrites
// every full row). K-summation order identical to the old core -> scores bitwise same.
__global__ __launch_bounds__(512) void k_scores(const u16* __restrict__ q,
                                                const u16* __restrict__ k,
                                                float* __restrict__ w) {
  __shared__ u16 lds[65536];
  const int wg = ((blockIdx.x & 7) * 18) + (blockIdx.x >> 3);   // [0,144)
  const int b = wg / 36;
  const int t = wg % 36;
  int mt = (int)((sqrtf(8.0f * (float)t + 1.0f) - 1.0f) * 0.5f);
  while ((mt + 1) * (mt + 2) / 2 <= t) ++mt;
  while (mt * (mt + 1) / 2 > t) --mt;
  const int nt = t - mt * (mt + 1) / 2;

  const u16* A  = q + (size_t)b * SEQ * DIM + (size_t)mt * 256 * DIM;
  const u16* Bt = k + (size_t)b * SEQ * DIM + (size_t)nt * 256 * DIM;

  const int tid = threadIdx.x;
  const int lane = tid & 63;
  const int wid = tid >> 6;
  const int srow = wid * 8 + (lane >> 3);
  const int gsrc = (lane & 7) ^ ((lane >> 3) & 7);
  const u16* pga = A + (size_t)srow * DIM + gsrc * 8;
  const u16* pgb = Bt + (size_t)srow * DIM + gsrc * 8;
  u16* stA = lds + wid * 512;
  u16* stB = lds + 32768 + wid * 512;

  const int wr = wid >> 2, wc = wid & 3;
  const int lrow = lane & 15, quad = lane >> 4;
  const int s = lrow & 7;
  const u16* aRd = lds + (wr * 128 + lrow) * 64;
  const u16* bRd = lds + 32768 + (wc * 64 + lrow) * 64;
  const int ga0 = (quad ^ s) << 3;
  const int ga1 = ga0 ^ 32;

  floatx4 acc[8][4] = {};
  core256(pga, pgb, aRd, bRd, stA, stB, ga0, ga1, acc, DIM / 128);

  float* C = w + (size_t)b * SEQ * SEQ
               + (size_t)(mt * 256 + wr * 128 + quad * 4) * SEQ
               + nt * 256 + wc * 64 + lrow;
  #pragma unroll
  for (int m = 0; m < 8; ++m)
    #pragma unroll
    for (int rr = 0; rr < 4; ++rr)
      #pragma unroll
      for (int n = 0; n < 4; ++n)
        C[(size_t)(m * 16 + rr) * SEQ + n * 16] = acc[m][n][rr] * 0.03125f;
}

// ---------------- BK=128 MFMA core (pv: grid-capped residency) ----------------
__device__ __forceinline__ void mfma_core128(const u16* __restrict__ A, int lda,
                                             const u16* __restrict__ Bt, int ldb,
                                             int kchunks, u16* lds,
                                             floatx4 acc[4][4]) {
  const int tid = threadIdx.x;
  const int lane = tid & 63;
  const int wid = tid >> 6;
  u16* lds_a = lds;            // 128 x 128 (swizzled granules)
  u16* lds_b = lds + 16384;

  const int srow4 = lane >> 4;          // 0..3
  const int sgr = lane & 15;
  const int gbase = sgr ^ srow4;        // even c
  const u16* ag0 = A + (size_t)(wid * 32 + srow4) * lda + gbase * 8;
  const u16* ag1 = A + (size_t)(wid * 32 + srow4) * lda + (gbase ^ 4) * 8;
  const u16* bg0 = Bt + (size_t)(wid * 32 + srow4) * ldb + gbase * 8;
  const u16* bg1 = Bt + (size_t)(wid * 32 + srow4) * ldb + (gbase ^ 4) * 8;
  u16* la = lds_a + wid * 4096;         // 32 rows x 128
  u16* lb = lds_b + wid * 4096;

  const int wm = (wid >> 1) * 64, wn = (wid & 1) * 64;
  const int lrow = lane & 15, quad = lane >> 4;
  const int s = lrow & 7;
  const u16* pa = lds_a + (wm + lrow) * 128;
  const u16* pb = lds_b + (wn + lrow) * 128;

  for (int kt = 0; kt < kchunks; ++kt) {
    #pragma unroll
    for (int c = 0; c < 8; ++c) {
      const u16* sa = ((c & 1) ? ag1 : ag0) + (size_t)(c * 4) * lda;
      async16(sa, la + c * 512);
    }
    #pragma unroll
    for (int c = 0; c < 8; ++c) {
      const u16* sb = ((c & 1) ? bg1 : bg0) + (size_t)(c * 4) * ldb;
      async16(sb, lb + c * 512);
    }
    ag0 += 128; ag1 += 128; bg0 += 128; bg1 += 128;
    __syncthreads();
    #pragma unroll
    for (int ks = 0; ks < 4; ++ks) {
      const int g = (((ks << 2) | quad) ^ s) << 3;
      bf16x8 af[4], bfr[4];
      #pragma unroll
      for (int t = 0; t < 4; ++t) af[t] = *(const bf16x8*)(pa + t * 2048 + g);
      #pragma unroll
      for (int t = 0; t < 4; ++t) bfr[t] = *(const bf16x8*)(pb + t * 2048 + g);
      #pragma unroll
      for (int i = 0; i < 4; ++i)
        #pragma unroll
        for (int j = 0; j < 4; ++j)
          acc[i][j] = __builtin_amdgcn_mfma_f32_16x16x32_bf16(af[i], bfr[j],
                                                              acc[i][j], 0, 0, 0);
    }
    __syncthreads();
  }
}

// ---------------- row softmax: weights fp32 (in-place) + P bf16 ----------------
__global__ __launch_bounds__(256) void k_softmax(float* __restrict__ w,
                                                 u16* __restrict__ P) {
  const int r = blockIdx.x;
  const int i = r & (SEQ - 1);
  const int len = i + 1;
  const int plen4 = (((i >> 7) + 1) << 7) >> 2;   // P write bound / float4
  float4* srow = (float4*)(w + (size_t)r * SEQ);
  ushort4* prow = (ushort4*)(P + (size_t)r * SEQ);
  const int tid = threadIdx.x;
  const int lane = tid & 63, wid = tid >> 6;
  __shared__ float rm[4], rs[4];

  float4 e[2];
  float mx = -1e30f;
  #pragma unroll
  for (int u = 0; u < 2; ++u) {
    int q4 = tid + u * 256;
    int j0 = q4 * 4;
    float4 v = make_float4(-1e30f, -1e30f, -1e30f, -1e30f);
    if (j0 < len) {
      v = srow[q4];
      v.x = (j0 + 0 < len) ? v.x : -1e30f;
      v.y = (j0 + 1 < len) ? v.y : -1e30f;
      v.z = (j0 + 2 < len) ? v.z : -1e30f;
      v.w = (j0 + 3 < len) ? v.w : -1e30f;
    }
    e[u] = v;
    mx = fmaxf(mx, fmaxf(fmaxf(v.x, v.y), fmaxf(v.z, v.w)));
  }
  #pragma unroll
  for (int o = 32; o >= 1; o >>= 1) mx = fmaxf(mx, __shfl_xor(mx, o, 64));
  if (lane == 0) rm[wid] = mx;
  __syncthreads();
  mx = fmaxf(fmaxf(rm[0], rm[1]), fmaxf(rm[2], rm[3]));

  float sum = 0.f;
  #pragma unroll
  for (int u = 0; u < 2; ++u) {
    e[u].x = __expf(e[u].x - mx);
    e[u].y = __expf(e[u].y - mx);
    e[u].z = __expf(e[u].z - mx);
    e[u].w = __expf(e[u].w - mx);
    sum += e[u].x + e[u].y + e[u].z + e[u].w;
  }
  #pragma unroll
  for (int o = 32; o >= 1; o >>= 1) sum += __shfl_xor(sum, o, 64);
  if (lane == 0) rs[wid] = sum;
  __syncthreads();
  sum = rs[0] + rs[1] + rs[2] + rs[3];
  const float inv = 1.0f / sum;

  #pragma unroll
  for (int u = 0; u < 2; ++u) {
    int q4 = tid + u * 256;
    int j0 = q4 * 4;
    float4 v;
    v.x = (j0 + 0 < len) ? e[u].x * inv : 0.f;
    v.y = (j0 + 1 < len) ? e[u].y * inv : 0.f;
    v.z = (j0 + 2 < len) ? e[u].z * inv : 0.f;
    v.w = (j0 + 3 < len) ? e[u].w * inv : 0.f;
    srow[q4] = v;                   // full fp32 row incl. zeros (output!)
    if (q4 < plen4) {
      ushort4 p;
      p.x = f32_to_bf16(v.x); p.y = f32_to_bf16(v.y);
      p.z = f32_to_bf16(v.z); p.w = f32_to_bf16(v.w);
      prow[q4] = p;
    }
  }
}

// ---------------- att_output = P @ v (vT layout), causal K truncation ----------------
__global__ __launch_bounds__(256) void k_pv(const u16* __restrict__ P,
                                            const u16* __restrict__ vT,
                                            float* __restrict__ out) {
  const int id = blockIdx.x;               // [0,512)
  const int mt = 15 - (id >> 5);           // [0,16), descending K (LPT)
  const int nt = (id >> 2) & 7;            // [0,8)
  const int b = id & 3;                    // [0,4)
  __shared__ u16 lds[32768];
  floatx4 acc[4][4] = {};
  mfma_core128(P + (size_t)b * SEQ * SEQ + (size_t)mt * 128 * SEQ, SEQ,
               vT + (size_t)b * DIM * SEQ + (size_t)nt * 128 * SEQ, SEQ,
               mt + 1, lds, acc);
  const int lane = threadIdx.x & 63, wid = threadIdx.x >> 6;
  const int wm = (wid >> 1) * 64, wn = (wid & 1) * 64;
  const int lrow = lane & 15, quad = lane >> 4;
  float* C = out + (size_t)b * SEQ * DIM
                 + (size_t)(mt * 128 + wm + quad * 4) * DIM + nt * 128 + wn + lrow;
  #pragma unroll
  for (int i = 0; i < 4; ++i)
    #pragma unroll
    for (int rr = 0; rr < 4; ++rr)
      #pragma unroll
      for (int j = 0; j < 4; ++j)
        C[(size_t)(i * 16 + rr) * DIM + j * 16] = acc[i][j][rr];
}

extern "C" void kernel_launch(void* const* d_in, const int* in_sizes, int n_in,
                              void* d_out, int out_size, void* d_ws, size_t ws_size,
                              hipStream_t stream) {
  const float* x  = (const float*)d_in[0];
  const float* Wq = (const float*)d_in[1];
  const float* Wk = (const float*)d_in[2];
  const float* Wv = (const float*)d_in[3];
  float* att_out = (float*)d_out;                    // [4,2048,1024]
  float* att_w   = (float*)d_out + 8388608;          // [4,2048,2048]

  // workspace layout (bf16 elements); ~107 MB
  u16* xb = (u16*)d_ws;             // 8,388,608   x bf16
  u16* wt = xb + 8388608;           // 3,145,728   Wq^T,Wk^T,Wv^T bf16
  u16* qk = wt + 3145728;           // 16,777,216  q,k bf16
  u16* vT = qk + 16777216;          // 8,388,608   v^T per batch
  u16* P  = vT + 8388608;           // 16,777,216  softmax probs bf16

  k_prep<<<7168, 256, 0, stream>>>(x, Wq, Wk, Wv, xb, wt);
  k_proj8<<<384, 512, 0, stream>>>(xb, wt, qk, vT);
  k_scores<<<144, 512, 0, stream>>>(qk, qk + 8388608, att_w);
  k_softmax<<<8192, 256, 0, stream>>>(att_w, P);
  k_pv<<<512, 256, 0, stream>>>(P, vT, att_out);
}